// Round 6
// baseline (289.824 us; speedup 1.0000x reference)
//
#include <hip/hip_runtime.h>

// GraphPolicyNetwork: 2-layer GraphSAGE (rank-1 weights -> scalar edge passes)
// + dense head [64x4096]@[4096x4096]. All tensors fp32 (proven round 4).
//
// R16: gemm = the three individually-proven pieces, composed without the R15
// mistake. R15 post-mortem: epilogue identical to R13 (WRITE 16.4MB proven)
// yet R15 showed WRITE 55MB / FETCH +10MB / VGPR 44->64 / first-dispatch
// 172us@1%occ => scratch spill caused by #pragma unroll of the 2-stage loop
// (doubled live ranges). R14 proved the same loop body clean at 44 VGPR.
// Here: (a) R14's LDS-staged-A body verbatim (kills the s_load serial chain
// that capped R11/R13 at 33-45% VALU), (b) stage loop NOT unrolled
// (#pragma unroll 1) with bvA/bvB scoped inside the stage, (c) R13's
// Cpart plain-store epilogue (no atomics - R14's 2x regression).
// Fast path needs 20 MB d_ws; falls back to proven R4 pipeline if smaller.

#define NTOT (64 * 4096)      // 262144 total nodes = 2^18
#define NHID 128
#define GK   4096             // GEMM K == N_NODES
#define KCH  256              // K per chunk (per gemm block, two LDS stages)
#define KCHUNKS 16
#define GKC  128              // K per LDS stage
#define NBINS 128             // dst-range buckets
#define BSZ   2048            // nodes per bucket (2^11)
#define BSH   11              // log2(BSZ)
#define CAP   17408           // bucket segment capacity (mean 16384 + 8 sigma)
#define NSL   4               // slices (blocks) per bucket in agg kernels
#define SCB   256             // scatter blocks

typedef unsigned int u32;

__device__ __forceinline__ float fast_tanh(float x) {
    float ax = fabsf(x);
    float t  = __expf(-2.0f * ax);
    float r  = (1.0f - t) / (1.0f + t);
    return copysignf(r, x);
}

// ======================= FAST PATH (ws >= 20 MB) ==========================

// ---- scatter: two-phase per-block reservation into bucket segments ----
__global__ void __launch_bounds__(1024) scatter_x(const int* __restrict__ src,
                                                  const int* __restrict__ dst,
                                                  int n_edges,
                                                  int* __restrict__ edge_cnt,
                                                  u32* __restrict__ packed) {
    __shared__ int lc[NBINS];
    __shared__ int lbase[NBINS];
    int t = threadIdx.x;
    if (t < NBINS) lc[t] = 0;
    __syncthreads();
    int per = (n_edges + gridDim.x - 1) / gridDim.x;   // <= 8192
    int e0 = blockIdx.x * per;
    int e1 = min(e0 + per, n_edges);

    int dreg[8], sreg[8];
#pragma unroll
    for (int i = 0; i < 8; ++i) {
        int e = e0 + t + i * 1024;
        bool ok = e < e1;
        int d = ok ? dst[e] : -1;
        dreg[i] = d;
        sreg[i] = ok ? src[e] : 0;
        if (ok) atomicAdd(&lc[d >> BSH], 1);
    }
    __syncthreads();
    if (t < NBINS) {
        lbase[t] = atomicAdd(&edge_cnt[t], lc[t]);
        lc[t] = 0;
    }
    __syncthreads();
#pragma unroll
    for (int i = 0; i < 8; ++i) {
        int d = dreg[i];
        if (d >= 0) {
            int b = d >> BSH;
            int pos = lbase[b] + atomicAdd(&lc[b], 1);
            if (pos < CAP)                    // p(overflow) ~ 0, fixed graph
                packed[(size_t)b * CAP + pos] =
                    ((u32)(d & (BSZ - 1)) << 18) | (u32)sreg[i];
        }
    }
}

// ---- agg1: LDS histogram (sum of nf[src], count) per bucket slice ----
__global__ void __launch_bounds__(1024) agg1_x(const u32* __restrict__ packed,
                                               const int* __restrict__ edge_cnt,
                                               const float* __restrict__ nf,
                                               float* __restrict__ part1) {
    __shared__ float lsum[BSZ];
    __shared__ float lcnt[BSZ];
    int t = threadIdx.x;
    int b = blockIdx.x, s = blockIdx.y;
    for (int i = t; i < BSZ; i += 1024) { lsum[i] = 0.0f; lcnt[i] = 0.0f; }
    __syncthreads();
    int en  = min(edge_cnt[b], CAP);
    int per = (en + NSL - 1) / NSL;
    int e0  = s * per;
    int e1  = min(e0 + per, en);
    const u32* pk = packed + (size_t)b * CAP;
    for (int e = e0 + t; e < e1; e += 1024) {
        u32 p = pk[e];
        int local = (int)(p >> 18);
        atomicAdd(&lsum[local], nf[p & 0x3FFFFu]);
        atomicAdd(&lcnt[local], 1.0f);
    }
    __syncthreads();
    float* dp = part1 + ((size_t)(b * NSL + s) * 2) * BSZ;
    for (int i = t; i < BSZ; i += 1024) { dp[i] = lsum[i]; dp[BSZ + i] = lcnt[i]; }
}

// ---- node1: reduce partials -> deg, hn; compute selfp, sp ----
__global__ void node1_x(const float* __restrict__ nf, const float* __restrict__ part1,
                        const float* __restrict__ w_s1, const float* __restrict__ w_n1,
                        const float* __restrict__ bb1,
                        const float* __restrict__ w_s2, const float* __restrict__ w_n2,
                        float* __restrict__ degf, float* __restrict__ selfp,
                        float* __restrict__ sp) {
    __shared__ float lws1[NHID], lwn1[NHID], lb1[NHID], lws2[NHID], lwn2[NHID];
    int tid = threadIdx.x;
    if (tid < NHID) {
        lws1[tid] = w_s1[tid];
        lwn1[tid] = w_n1[tid];
        lb1[tid]  = bb1[tid];
        lws2[tid] = w_s2[tid];
        lwn2[tid] = w_n2[tid];
    }
    __syncthreads();
    int v = blockIdx.x * blockDim.x + tid;
    int b = v >> BSH, local = v & (BSZ - 1);
    float sum = 0.0f, cf = 0.0f;
#pragma unroll
    for (int s = 0; s < NSL; ++s) {
        const float* dp = part1 + ((size_t)(b * NSL + s) * 2) * BSZ;
        sum += dp[local];
        cf  += dp[BSZ + local];
    }
    float hn = sum / fmaxf(cf, 1.0f);
    float f = nf[v];
    float a = 0.0f, s2 = 0.0f;
#pragma unroll 8
    for (int j = 0; j < NHID; ++j) {
        float t = fast_tanh(fmaf(f, lws1[j], fmaf(hn, lwn1[j], lb1[j])));
        a  = fmaf(t, lws2[j], a);
        s2 = fmaf(t, lwn2[j], s2);
    }
    degf[v]  = cf;
    selfp[v] = a;
    sp[v]    = s2;
}

// ---- agg2: LDS histogram (sum of sp[src]) per bucket slice ----
__global__ void __launch_bounds__(1024) agg2_x(const u32* __restrict__ packed,
                                               const int* __restrict__ edge_cnt,
                                               const float* __restrict__ spv,
                                               float* __restrict__ part2) {
    __shared__ float lsum[BSZ];
    int t = threadIdx.x;
    int b = blockIdx.x, s = blockIdx.y;
    for (int i = t; i < BSZ; i += 1024) lsum[i] = 0.0f;
    __syncthreads();
    int en  = min(edge_cnt[b], CAP);
    int per = (en + NSL - 1) / NSL;
    int e0  = s * per;
    int e1  = min(e0 + per, en);
    const u32* pk = packed + (size_t)b * CAP;
    for (int e = e0 + t; e < e1; e += 1024) {
        u32 p = pk[e];
        atomicAdd(&lsum[p >> 18], spv[p & 0x3FFFFu]);
    }
    __syncthreads();
    float* dp = part2 + (size_t)(b * NSL + s) * BSZ;
    for (int i = t; i < BSZ; i += 1024) dp[i] = lsum[i];
}

// ---- node2: reduce partials2; out1 (fp32); h2t K-major ----
__global__ void node2_x(const float* __restrict__ selfp, const float* __restrict__ part2,
                        const float* __restrict__ degf, const float* __restrict__ b2p,
                        float* __restrict__ out1, float* __restrict__ h2t) {
    int v = blockIdx.x * blockDim.x + threadIdx.x;
    int b = v >> BSH, local = v & (BSZ - 1);
    float agg2 = 0.0f;
#pragma unroll
    for (int s = 0; s < NSL; ++s)
        agg2 += part2[(size_t)(b * NSL + s) * BSZ + local];
    float o = selfp[v] + agg2 / fmaxf(degf[v], 1.0f) + b2p[0];
    out1[v] = o;
    int r = v >> 12;     // graph (row) index 0..63
    int k = v & 4095;    // node-in-graph (K) index
    h2t[k * 64 + r] = fast_tanh(o);
}

// ---- GEMM: 128-col x 64-row tile, LDS-staged A, Cpart stores ----
// Per k: 1 float2 B VMEM (8-deep dbuf prefetch) + wave-uniform ds_read A
// (1k ahead) + 16 FMA. Stage loop NOT unrolled (R15 spill lesson); bvA/bvB
// scoped inside the stage. LDS 33KB; grid 32x16 = 512 blocks, 512 thr.
__global__ void __launch_bounds__(512, 4) gemm_x(const float* __restrict__ h2t,
                                                 const float* __restrict__ w3,
                                                 float* __restrict__ Cpart) {
    __shared__ float As[GKC * 64 + 64];   // pad: tail A-prefetch reads k==GKC
    int t    = threadIdx.x;
    int lane = t & 63;
    int wv   = t >> 6;                    // 0..7
    int colb = blockIdx.x * 128 + lane * 2;
    int k0   = blockIdx.y * KCH;
    int row0 = __builtin_amdgcn_readfirstlane(wv * 8);

    const float* Asw = As + row0;
    float4* sA = (float4*)As;

    float2 acc[8];
#pragma unroll
    for (int r = 0; r < 8; ++r) { acc[r].x = 0.0f; acc[r].y = 0.0f; }

#pragma unroll 1
    for (int st = 0; st < 2; ++st) {
        const float* wps = w3 + (size_t)(k0 + st * GKC) * GK + colb;
        const float4* gA = (const float4*)(h2t + (size_t)(k0 + st * GKC) * 64);
        if (st) __syncthreads();          // all waves done reading prev stage
#pragma unroll
        for (int i = 0; i < 4; ++i) sA[t + i * 512] = gA[t + i * 512];

        float2 bvA[8], bvB[8];
#pragma unroll
        for (int j = 0; j < 8; ++j)
            bvA[j] = *(const float2*)(wps + (size_t)j * GK);
        __syncthreads();                  // A staged

        float4 a0 = *(const float4*)(Asw);
        float4 a1 = *(const float4*)(Asw + 4);

        for (int kk = 0; kk < GKC; kk += 16) {
#pragma unroll
            for (int j = 0; j < 8; ++j)
                bvB[j] = *(const float2*)(wps + (size_t)(kk + 8 + j) * GK);
#pragma unroll
            for (int j = 0; j < 8; ++j) {
                const float* An = Asw + (kk + j + 1) * 64;   // uniform bcast
                float4 n0 = *(const float4*)(An);
                float4 n1 = *(const float4*)(An + 4);
                float2 b  = bvA[j];
                acc[0].x = fmaf(a0.x, b.x, acc[0].x); acc[0].y = fmaf(a0.x, b.y, acc[0].y);
                acc[1].x = fmaf(a0.y, b.x, acc[1].x); acc[1].y = fmaf(a0.y, b.y, acc[1].y);
                acc[2].x = fmaf(a0.z, b.x, acc[2].x); acc[2].y = fmaf(a0.z, b.y, acc[2].y);
                acc[3].x = fmaf(a0.w, b.x, acc[3].x); acc[3].y = fmaf(a0.w, b.y, acc[3].y);
                acc[4].x = fmaf(a1.x, b.x, acc[4].x); acc[4].y = fmaf(a1.x, b.y, acc[4].y);
                acc[5].x = fmaf(a1.y, b.x, acc[5].x); acc[5].y = fmaf(a1.y, b.y, acc[5].y);
                acc[6].x = fmaf(a1.z, b.x, acc[6].x); acc[6].y = fmaf(a1.z, b.y, acc[6].y);
                acc[7].x = fmaf(a1.w, b.x, acc[7].x); acc[7].y = fmaf(a1.w, b.y, acc[7].y);
                a0 = n0; a1 = n1;
            }
            if (kk + 16 < GKC) {
#pragma unroll
                for (int j = 0; j < 8; ++j)
                    bvA[j] = *(const float2*)(wps + (size_t)(kk + 16 + j) * GK);
            }
#pragma unroll
            for (int j = 0; j < 8; ++j) {
                const float* An = Asw + (kk + 8 + j + 1) * 64;
                float4 n0 = *(const float4*)(An);
                float4 n1 = *(const float4*)(An + 4);
                float2 b  = bvB[j];
                acc[0].x = fmaf(a0.x, b.x, acc[0].x); acc[0].y = fmaf(a0.x, b.y, acc[0].y);
                acc[1].x = fmaf(a0.y, b.x, acc[1].x); acc[1].y = fmaf(a0.y, b.y, acc[1].y);
                acc[2].x = fmaf(a0.z, b.x, acc[2].x); acc[2].y = fmaf(a0.z, b.y, acc[2].y);
                acc[3].x = fmaf(a0.w, b.x, acc[3].x); acc[3].y = fmaf(a0.w, b.y, acc[3].y);
                acc[4].x = fmaf(a1.x, b.x, acc[4].x); acc[4].y = fmaf(a1.x, b.y, acc[4].y);
                acc[5].x = fmaf(a1.y, b.x, acc[5].x); acc[5].y = fmaf(a1.y, b.y, acc[5].y);
                acc[6].x = fmaf(a1.z, b.x, acc[6].x); acc[6].y = fmaf(a1.z, b.y, acc[6].y);
                acc[7].x = fmaf(a1.w, b.x, acc[7].x); acc[7].y = fmaf(a1.w, b.y, acc[7].y);
                a0 = n0; a1 = n1;
            }
        }
    }

    float* Cp = Cpart + (size_t)blockIdx.y * NTOT + (size_t)row0 * GK + colb;
#pragma unroll
    for (int r = 0; r < 8; ++r) *(float2*)(Cp + (size_t)r * GK) = acc[r];
}

// ---- reduce K-chunk partials + b3 -> out2 (float4) ----
__global__ void reduce_x(const float4* __restrict__ Cpart, const float4* __restrict__ b3v,
                         float4* __restrict__ out2) {
    int v = blockIdx.x * blockDim.x + threadIdx.x;   // float4 index, NTOT/4
    float4 s = b3v[v & 1023];
#pragma unroll
    for (int kc = 0; kc < KCHUNKS; ++kc) {
        float4 c = Cpart[(size_t)kc * (NTOT / 4) + v];
        s.x += c.x; s.y += c.y; s.z += c.z; s.w += c.w;
    }
    out2[v] = s;
}

// ================== FALLBACK PATH (proven R4 pipeline) ====================

__global__ void edge_pass1_f(const int* __restrict__ src, const int* __restrict__ dst,
                             const float* __restrict__ nf, float* __restrict__ agg,
                             float* __restrict__ deg, int n_edges) {
    int e = blockIdx.x * blockDim.x + threadIdx.x;
    if (e >= n_edges) return;
    int s = src[e], d = dst[e];
    atomicAdd(&agg[d], nf[s]);
    atomicAdd(&deg[d], 1.0f);
}

__global__ void node1_f(const float* __restrict__ nf, float* s0,
                        const float* __restrict__ deg,
                        const float* __restrict__ w_s1, const float* __restrict__ w_n1,
                        const float* __restrict__ bb1,
                        const float* __restrict__ w_s2, const float* __restrict__ w_n2,
                        float* __restrict__ sp) {
    __shared__ float lws1[NHID], lwn1[NHID], lb1[NHID], lws2[NHID], lwn2[NHID];
    int tid = threadIdx.x;
    if (tid < NHID) {
        lws1[tid] = w_s1[tid];
        lwn1[tid] = w_n1[tid];
        lb1[tid]  = bb1[tid];
        lws2[tid] = w_s2[tid];
        lwn2[tid] = w_n2[tid];
    }
    __syncthreads();
    int v = blockIdx.x * blockDim.x + tid;
    float f  = nf[v];
    float hn = s0[v] / fmaxf(deg[v], 1.0f);
    float a = 0.0f, s = 0.0f;
#pragma unroll 8
    for (int j = 0; j < NHID; ++j) {
        float t = fast_tanh(fmaf(f, lws1[j], fmaf(hn, lwn1[j], lb1[j])));
        a = fmaf(t, lws2[j], a);
        s = fmaf(t, lwn2[j], s);
    }
    s0[v] = a;
    sp[v] = s;
}

__global__ void edge_pass2_f(const int* __restrict__ src, const int* __restrict__ dst,
                             const float* __restrict__ sp, float* __restrict__ agg2,
                             int n_edges) {
    int e = blockIdx.x * blockDim.x + threadIdx.x;
    if (e >= n_edges) return;
    atomicAdd(&agg2[dst[e]], sp[src[e]]);
}

__global__ void node2_f(const float* __restrict__ s0, const float* __restrict__ agg2,
                        const float* __restrict__ deg, const float* __restrict__ b2p,
                        const float* __restrict__ b3p,
                        float* __restrict__ out1, float* __restrict__ h2t,
                        float* __restrict__ out2) {
    int v = blockIdx.x * blockDim.x + threadIdx.x;
    float o = s0[v] + agg2[v] / fmaxf(deg[v], 1.0f) + b2p[0];
    out1[v] = o;
    int r = v >> 12;
    int k = v & 4095;
    h2t[k * 64 + r] = fast_tanh(o);
    out2[v] = b3p[v & 4095];
}

__global__ void __launch_bounds__(256) gemm_f(const float* __restrict__ h2t,
                                              const float* __restrict__ w3,
                                              float* __restrict__ out2) {
    int n  = blockIdx.x * 256 + threadIdx.x;
    int k0 = blockIdx.y * KCH;
    float acc[64];
#pragma unroll
    for (int r = 0; r < 64; ++r) acc[r] = 0.0f;
    for (int k = k0; k < k0 + KCH; ++k) {
        float bv = w3[(size_t)k * GK + n];
        const float* Ak = h2t + k * 64;
#pragma unroll
        for (int r = 0; r < 64; ++r) acc[r] = fmaf(Ak[r], bv, acc[r]);
    }
#pragma unroll
    for (int r = 0; r < 64; ++r) atomicAdd(&out2[r * GK + n], acc[r]);
}

// ==========================================================================

extern "C" void kernel_launch(void* const* d_in, const int* in_sizes, int n_in,
                              void* d_out, int out_size, void* d_ws, size_t ws_size,
                              hipStream_t stream) {
    const float* nf  = (const float*)d_in[0];
    const int*   src = (const int*)d_in[1];
    const int*   dst = (const int*)d_in[2];
    const float* ws1 = (const float*)d_in[3];
    const float* wn1 = (const float*)d_in[4];
    const float* b1  = (const float*)d_in[5];
    const float* ws2 = (const float*)d_in[6];
    const float* wn2 = (const float*)d_in[7];
    const float* b2  = (const float*)d_in[8];
    const float* w3  = (const float*)d_in[9];
    const float* b3  = (const float*)d_in[10];
    float* out1 = (float*)d_out;
    float* out2 = (float*)d_out + NTOT;

    int n_edges = in_sizes[1];
    int eb = (n_edges + 255) / 256;

    if (ws_size >= (size_t)20 * 1024 * 1024 && n_edges <= (1 << 21)) {
        // -------- fast path: 20 MB layout --------
        // [0, 8.5M)      packed   (NBINS*CAP u32 = 8912896 B)
        // [8.5M, 16.5M)  part     (NBINS*NSL*2*BSZ f32 = 8 MB)
        // [16.5M, 17.5M) degf     [17.5M, 18.5M) selfp
        // [18.5M, 19.5M) spbuf/h2t
        // [19.5M, ...)   edge_cnt (NBINS ints)
        // Cpart (16 MB) overlays [0, 16M): packed+part dead after node2.
        char*  base     = (char*)d_ws;
        u32*   packed   = (u32*)base;
        float* part     = (float*)(base + 8912896);
        float* degf     = (float*)(base + 17301504);
        float* selfp    = (float*)(base + 18350080);
        float* spbuf    = (float*)(base + 19398656);
        int*   edge_cnt = (int*)(base + 20447232);
        float* h2t      = spbuf;          // alias: sp dead after agg2_x
        float* Cpart    = (float*)base;

        (void)hipMemsetAsync(edge_cnt, 0, NBINS * sizeof(int), stream);
        scatter_x<<<SCB, 1024, 0, stream>>>(src, dst, n_edges, edge_cnt, packed);
        agg1_x<<<dim3(NBINS, NSL), 1024, 0, stream>>>(packed, edge_cnt, nf, part);
        node1_x<<<NTOT / 256, 256, 0, stream>>>(nf, part, ws1, wn1, b1, ws2, wn2,
                                                degf, selfp, spbuf);
        agg2_x<<<dim3(NBINS, NSL), 1024, 0, stream>>>(packed, edge_cnt, spbuf, part);
        node2_x<<<NTOT / 256, 256, 0, stream>>>(selfp, part, degf, b2, out1, h2t);
        gemm_x<<<dim3(GK / 128, KCHUNKS), 512, 0, stream>>>(h2t, w3, Cpart);
        reduce_x<<<NTOT / 4 / 256, 256, 0, stream>>>((const float4*)Cpart,
                                                     (const float4*)b3, (float4*)out2);
    } else {
        // -------- fallback: proven R4 pipeline (4.19 MB) --------
        float* ws = (float*)d_ws;
        float* S0 = ws;            // agg -> selfpart
        float* S1 = ws + 1 * NTOT; // deg
        float* S2 = ws + 2 * NTOT; // agg2
        float* S3 = ws + 3 * NTOT; // sp -> h2t

        (void)hipMemsetAsync(S0, 0, (size_t)3 * NTOT * sizeof(float), stream);
        edge_pass1_f<<<eb, 256, 0, stream>>>(src, dst, nf, S0, S1, n_edges);
        node1_f<<<NTOT / 256, 256, 0, stream>>>(nf, S0, S1, ws1, wn1, b1, ws2, wn2, S3);
        edge_pass2_f<<<eb, 256, 0, stream>>>(src, dst, S3, S2, n_edges);
        node2_f<<<NTOT / 256, 256, 0, stream>>>(S0, S2, S1, b2, b3, out1, S3, out2);
        gemm_f<<<dim3(GK / 256, KCHUNKS), 256, 0, stream>>>(S3, w3, out2);
    }
}

// Round 9
// 229.691 us; speedup vs baseline: 1.2618x; 1.2618x over previous
//
#include <hip/hip_runtime.h>

// GraphPolicyNetwork: 2-layer GraphSAGE (rank-1 weights -> scalar edge passes)
// + dense head [64x4096]@[4096x4096]. All tensors fp32 (proven round 4).
//
// R19 == R17/R18 resubmit (both benches died with "MI355X container failed
// twice" -- a container/acquisition-stage error, not a kernel error; R2->R3
// precedent: identical resubmit passed and measured. Full audit x2 found no
// fault mechanism: uniform barriers, bounded loops, disjoint ws map, guarded
// CAP, 10.75KB max LDS). If this third attempt fails, the source is presumed
// guilty and the next round bisects (R13 graph side + this gemm).
// Changes vs R16:
// (1) gemm_x reverted to R11 exact (proven 49-52us, VGPR 32). The
// LDS-staged-A line (R14/15/16: 103/76/88us) is abandoned: all three showed
// scratch-spill signatures (extra WRITE_SIZE, first-dispatch stall @ ~1-5%
// occupancy, VGPR creep) -- true reg pressure exceeded the 128 cap.
// (2) Graph side restructured for fusion: NBINS 128->256, BSZ 2048->1024 so
// ONE 1024-thread block owns ONE bucket (thread t = node t). agg1+node1 and
// agg2+node2 fuse into agn1_x/agn2_x: histogram stays in LDS, node epilogue
// reads it directly. Deletes part1/part2 (24MB round-trip), 2 launches, 2
// pipeline drains. 256 blocks = 1 block/CU on all CUs.
// Fast path needs 20 MB d_ws; falls back to proven R4 pipeline if smaller.

#define NTOT (64 * 4096)      // 262144 total nodes = 2^18
#define NHID 128
#define GK   4096             // GEMM K == N_NODES
#define KCH  256              // K per chunk
#define KCHUNKS 16
#define NBINS 256             // dst-range buckets
#define BSZ   1024            // nodes per bucket (2^10)
#define BSH   10              // log2(BSZ)
#define CAP   8960            // bucket capacity (mean 8192 + ~8.5 sigma)
#define SCB   256             // scatter blocks

typedef unsigned int u32;

__device__ __forceinline__ float fast_tanh(float x) {
    float ax = fabsf(x);
    float t  = __expf(-2.0f * ax);
    float r  = (1.0f - t) / (1.0f + t);
    return copysignf(r, x);
}

// ======================= FAST PATH (ws >= 20 MB) ==========================

// ---- scatter: two-phase per-block reservation into bucket segments ----
// Each thread owns <=8 edges, cached in registers across all 3 phases.
__global__ void __launch_bounds__(1024) scatter_x(const int* __restrict__ src,
                                                  const int* __restrict__ dst,
                                                  int n_edges,
                                                  int* __restrict__ edge_cnt,
                                                  u32* __restrict__ packed) {
    __shared__ int lc[NBINS];
    __shared__ int lbase[NBINS];
    int t = threadIdx.x;
    if (t < NBINS) lc[t] = 0;
    __syncthreads();
    int per = (n_edges + gridDim.x - 1) / gridDim.x;   // <= 8192
    int e0 = blockIdx.x * per;
    int e1 = min(e0 + per, n_edges);

    int dreg[8], sreg[8];
#pragma unroll
    for (int i = 0; i < 8; ++i) {
        int e = e0 + t + i * 1024;
        bool ok = e < e1;
        int d = ok ? dst[e] : -1;
        dreg[i] = d;
        sreg[i] = ok ? src[e] : 0;
        if (ok) atomicAdd(&lc[d >> BSH], 1);
    }
    __syncthreads();
    if (t < NBINS) {
        lbase[t] = atomicAdd(&edge_cnt[t], lc[t]);
        lc[t] = 0;
    }
    __syncthreads();
#pragma unroll
    for (int i = 0; i < 8; ++i) {
        int d = dreg[i];
        if (d >= 0) {
            int b = d >> BSH;
            int pos = lbase[b] + atomicAdd(&lc[b], 1);
            if (pos < CAP)                    // p(overflow) ~ 0, fixed graph
                packed[(size_t)b * CAP + pos] =
                    ((u32)(d & (BSZ - 1)) << 18) | (u32)sreg[i];
        }
    }
}

// ---- fused agg1+node1: LDS histogram + per-node layer-1/2 math ----
// One block per bucket; thread t = node t. No global partials.
__global__ void __launch_bounds__(1024) agn1_x(const u32* __restrict__ packed,
                                               const int* __restrict__ edge_cnt,
                                               const float* __restrict__ nf,
                                               const float* __restrict__ w_s1,
                                               const float* __restrict__ w_n1,
                                               const float* __restrict__ bb1,
                                               const float* __restrict__ w_s2,
                                               const float* __restrict__ w_n2,
                                               float* __restrict__ degf,
                                               float* __restrict__ selfp,
                                               float* __restrict__ sp) {
    __shared__ float lsum[BSZ];
    __shared__ float lcnt[BSZ];
    __shared__ float lws1[NHID], lwn1[NHID], lb1[NHID], lws2[NHID], lwn2[NHID];
    int t = threadIdx.x;
    int b = blockIdx.x;
    lsum[t] = 0.0f;
    lcnt[t] = 0.0f;
    if (t < NHID) {
        lws1[t] = w_s1[t];
        lwn1[t] = w_n1[t];
        lb1[t]  = bb1[t];
        lws2[t] = w_s2[t];
        lwn2[t] = w_n2[t];
    }
    __syncthreads();
    int en = min(edge_cnt[b], CAP);
    const u32* pk = packed + (size_t)b * CAP;
    for (int e = t; e < en; e += 1024) {
        u32 p = pk[e];
        int local = (int)(p >> 18);
        atomicAdd(&lsum[local], nf[p & 0x3FFFFu]);
        atomicAdd(&lcnt[local], 1.0f);
    }
    __syncthreads();
    int v = b * BSZ + t;
    float cf = lcnt[t];
    float hn = lsum[t] / fmaxf(cf, 1.0f);
    float f  = nf[v];
    float a = 0.0f, s2 = 0.0f;
#pragma unroll 8
    for (int j = 0; j < NHID; ++j) {
        float th = fast_tanh(fmaf(f, lws1[j], fmaf(hn, lwn1[j], lb1[j])));
        a  = fmaf(th, lws2[j], a);
        s2 = fmaf(th, lwn2[j], s2);
    }
    degf[v]  = cf;
    selfp[v] = a;
    sp[v]    = s2;
}

// ---- fused agg2+node2: LDS histogram + out1 / h2t epilogue ----
__global__ void __launch_bounds__(1024) agn2_x(const u32* __restrict__ packed,
                                               const int* __restrict__ edge_cnt,
                                               const float* __restrict__ spv,
                                               const float* __restrict__ selfp,
                                               const float* __restrict__ degf,
                                               const float* __restrict__ b2p,
                                               float* __restrict__ out1,
                                               float* __restrict__ h2t) {
    __shared__ float lsum[BSZ];
    int t = threadIdx.x;
    int b = blockIdx.x;
    lsum[t] = 0.0f;
    __syncthreads();
    int en = min(edge_cnt[b], CAP);
    const u32* pk = packed + (size_t)b * CAP;
    for (int e = t; e < en; e += 1024) {
        u32 p = pk[e];
        atomicAdd(&lsum[p >> 18], spv[p & 0x3FFFFu]);
    }
    __syncthreads();
    int v = b * BSZ + t;
    float o = selfp[v] + lsum[t] / fmaxf(degf[v], 1.0f) + b2p[0];
    out1[v] = o;
    int r = v >> 12;     // graph (row) index 0..63
    int k = v & 4095;    // node-in-graph (K) index
    h2t[k * 64 + r] = fast_tanh(o);
}

// ---- GEMM (R11 exact, proven 49-52us): 64x64 tile, 8 waves x 8 rows ----
__global__ void __launch_bounds__(512, 4) gemm_x(const float* __restrict__ h2t,
                                                 const float* __restrict__ w3,
                                                 float* __restrict__ Cpart) {
    int lane = threadIdx.x & 63;
    int wv   = threadIdx.x >> 6;          // 0..7
    int col  = blockIdx.x * 64 + lane;
    int k0   = blockIdx.y * KCH;
    int row0 = __builtin_amdgcn_readfirstlane(wv * 8);

    const float* Ap = h2t + (size_t)k0 * 64 + row0;
    const float* wp = w3 + (size_t)k0 * GK + col;

    float acc[8];
#pragma unroll
    for (int r = 0; r < 8; ++r) acc[r] = 0.0f;

    float bvA[8], bvB[8];
    float avA[8], avB[8];

#pragma unroll
    for (int j = 0; j < 8; ++j) bvA[j] = wp[(size_t)j * GK];
#pragma unroll
    for (int r = 0; r < 8; ++r) avA[r] = Ap[r];

    for (int kk = 0; kk < KCH; kk += 16) {
#pragma unroll
        for (int j = 0; j < 8; ++j) bvB[j] = wp[(size_t)(kk + 8 + j) * GK];
#pragma unroll
        for (int j = 0; j < 8; ++j) {
            const float* An = Ap + (size_t)(kk + j + 1) * 64;
            if ((j & 1) == 0) {
#pragma unroll
                for (int r = 0; r < 8; ++r) avB[r] = An[r];
                float b = bvA[j];
#pragma unroll
                for (int r = 0; r < 8; ++r) acc[r] = fmaf(avA[r], b, acc[r]);
            } else {
#pragma unroll
                for (int r = 0; r < 8; ++r) avA[r] = An[r];
                float b = bvA[j];
#pragma unroll
                for (int r = 0; r < 8; ++r) acc[r] = fmaf(avB[r], b, acc[r]);
            }
        }
        if (kk + 16 < KCH) {
#pragma unroll
            for (int j = 0; j < 8; ++j) bvA[j] = wp[(size_t)(kk + 16 + j) * GK];
        }
#pragma unroll
        for (int j = 0; j < 8; ++j) {
            int kn = kk + 8 + j + 1;
            if (kn > KCH - 1) kn = KCH - 1;
            const float* An = Ap + (size_t)kn * 64;
            if ((j & 1) == 0) {
#pragma unroll
                for (int r = 0; r < 8; ++r) avB[r] = An[r];
                float b = bvB[j];
#pragma unroll
                for (int r = 0; r < 8; ++r) acc[r] = fmaf(avA[r], b, acc[r]);
            } else {
#pragma unroll
                for (int r = 0; r < 8; ++r) avA[r] = An[r];
                float b = bvB[j];
#pragma unroll
                for (int r = 0; r < 8; ++r) acc[r] = fmaf(avB[r], b, acc[r]);
            }
        }
    }

    float* Cp = Cpart + (size_t)blockIdx.y * NTOT + (size_t)row0 * GK + col;
#pragma unroll
    for (int r = 0; r < 8; ++r) Cp[(size_t)r * GK] = acc[r];
}

// ---- reduce K-chunk partials + b3 -> out2 (float4) ----
__global__ void reduce_x(const float4* __restrict__ Cpart, const float4* __restrict__ b3v,
                         float4* __restrict__ out2) {
    int v = blockIdx.x * blockDim.x + threadIdx.x;   // float4 index, NTOT/4
    float4 s = b3v[v & 1023];
#pragma unroll
    for (int kc = 0; kc < KCHUNKS; ++kc) {
        float4 c = Cpart[(size_t)kc * (NTOT / 4) + v];
        s.x += c.x; s.y += c.y; s.z += c.z; s.w += c.w;
    }
    out2[v] = s;
}

// ================== FALLBACK PATH (proven R4 pipeline) ====================

__global__ void edge_pass1_f(const int* __restrict__ src, const int* __restrict__ dst,
                             const float* __restrict__ nf, float* __restrict__ agg,
                             float* __restrict__ deg, int n_edges) {
    int e = blockIdx.x * blockDim.x + threadIdx.x;
    if (e >= n_edges) return;
    int s = src[e], d = dst[e];
    atomicAdd(&agg[d], nf[s]);
    atomicAdd(&deg[d], 1.0f);
}

__global__ void node1_f(const float* __restrict__ nf, float* s0,
                        const float* __restrict__ deg,
                        const float* __restrict__ w_s1, const float* __restrict__ w_n1,
                        const float* __restrict__ bb1,
                        const float* __restrict__ w_s2, const float* __restrict__ w_n2,
                        float* __restrict__ sp) {
    __shared__ float lws1[NHID], lwn1[NHID], lb1[NHID], lws2[NHID], lwn2[NHID];
    int tid = threadIdx.x;
    if (tid < NHID) {
        lws1[tid] = w_s1[tid];
        lwn1[tid] = w_n1[tid];
        lb1[tid]  = bb1[tid];
        lws2[tid] = w_s2[tid];
        lwn2[tid] = w_n2[tid];
    }
    __syncthreads();
    int v = blockIdx.x * blockDim.x + tid;
    float f  = nf[v];
    float hn = s0[v] / fmaxf(deg[v], 1.0f);
    float a = 0.0f, s = 0.0f;
#pragma unroll 8
    for (int j = 0; j < NHID; ++j) {
        float t = fast_tanh(fmaf(f, lws1[j], fmaf(hn, lwn1[j], lb1[j])));
        a = fmaf(t, lws2[j], a);
        s = fmaf(t, lwn2[j], s);
    }
    s0[v] = a;
    sp[v] = s;
}

__global__ void edge_pass2_f(const int* __restrict__ src, const int* __restrict__ dst,
                             const float* __restrict__ sp, float* __restrict__ agg2,
                             int n_edges) {
    int e = blockIdx.x * blockDim.x + threadIdx.x;
    if (e >= n_edges) return;
    atomicAdd(&agg2[dst[e]], sp[src[e]]);
}

__global__ void node2_f(const float* __restrict__ s0, const float* __restrict__ agg2,
                        const float* __restrict__ deg, const float* __restrict__ b2p,
                        const float* __restrict__ b3p,
                        float* __restrict__ out1, float* __restrict__ h2t,
                        float* __restrict__ out2) {
    int v = blockIdx.x * blockDim.x + threadIdx.x;
    float o = s0[v] + agg2[v] / fmaxf(deg[v], 1.0f) + b2p[0];
    out1[v] = o;
    int r = v >> 12;
    int k = v & 4095;
    h2t[k * 64 + r] = fast_tanh(o);
    out2[v] = b3p[v & 4095];
}

__global__ void __launch_bounds__(256) gemm_f(const float* __restrict__ h2t,
                                              const float* __restrict__ w3,
                                              float* __restrict__ out2) {
    int n  = blockIdx.x * 256 + threadIdx.x;
    int k0 = blockIdx.y * KCH;
    float acc[64];
#pragma unroll
    for (int r = 0; r < 64; ++r) acc[r] = 0.0f;
    for (int k = k0; k < k0 + KCH; ++k) {
        float bv = w3[(size_t)k * GK + n];
        const float* Ak = h2t + k * 64;
#pragma unroll
        for (int r = 0; r < 64; ++r) acc[r] = fmaf(Ak[r], bv, acc[r]);
    }
#pragma unroll
    for (int r = 0; r < 64; ++r) atomicAdd(&out2[r * GK + n], acc[r]);
}

// ==========================================================================

extern "C" void kernel_launch(void* const* d_in, const int* in_sizes, int n_in,
                              void* d_out, int out_size, void* d_ws, size_t ws_size,
                              hipStream_t stream) {
    const float* nf  = (const float*)d_in[0];
    const int*   src = (const int*)d_in[1];
    const int*   dst = (const int*)d_in[2];
    const float* ws1 = (const float*)d_in[3];
    const float* wn1 = (const float*)d_in[4];
    const float* b1  = (const float*)d_in[5];
    const float* ws2 = (const float*)d_in[6];
    const float* wn2 = (const float*)d_in[7];
    const float* b2  = (const float*)d_in[8];
    const float* w3  = (const float*)d_in[9];
    const float* b3  = (const float*)d_in[10];
    float* out1 = (float*)d_out;
    float* out2 = (float*)d_out + NTOT;

    int n_edges = in_sizes[1];
    int eb = (n_edges + 255) / 256;

    if (ws_size >= (size_t)20 * 1024 * 1024 && n_edges <= (1 << 21)) {
        // -------- fast path: 20 MB layout --------
        // packed  [0, 9.2M)   (NBINS*CAP u32 = 9175040 B)
        // degf    [10M, 11M)  selfp [11M, 12M)  sp [12M, 13M)
        // h2t     [16M, 17M)
        // edge_cnt @ 17M      (NBINS ints)
        // Cpart overlays [0, 16M): packed/degf/selfp/sp dead when gemm runs;
        // h2t at 16M is outside Cpart (ends exactly at 16777216).
        char*  base     = (char*)d_ws;
        u32*   packed   = (u32*)base;
        float* degf     = (float*)(base + 10485760);
        float* selfp    = (float*)(base + 11534336);
        float* spbuf    = (float*)(base + 12582912);
        float* h2t      = (float*)(base + 16777216);
        int*   edge_cnt = (int*)(base + 17825792);
        float* Cpart    = (float*)base;

        (void)hipMemsetAsync(edge_cnt, 0, NBINS * sizeof(int), stream);
        scatter_x<<<SCB, 1024, 0, stream>>>(src, dst, n_edges, edge_cnt, packed);
        agn1_x<<<NBINS, 1024, 0, stream>>>(packed, edge_cnt, nf, ws1, wn1, b1,
                                           ws2, wn2, degf, selfp, spbuf);
        agn2_x<<<NBINS, 1024, 0, stream>>>(packed, edge_cnt, spbuf, selfp, degf,
                                           b2, out1, h2t);
        gemm_x<<<dim3(GK / 64, KCHUNKS), 512, 0, stream>>>(h2t, w3, Cpart);
        reduce_x<<<NTOT / 4 / 256, 256, 0, stream>>>((const float4*)Cpart,
                                                     (const float4*)b3, (float4*)out2);
    } else {
        // -------- fallback: proven R4 pipeline (4.19 MB) --------
        float* ws = (float*)d_ws;
        float* S0 = ws;            // agg -> selfpart
        float* S1 = ws + 1 * NTOT; // deg
        float* S2 = ws + 2 * NTOT; // agg2
        float* S3 = ws + 3 * NTOT; // sp -> h2t

        (void)hipMemsetAsync(S0, 0, (size_t)3 * NTOT * sizeof(float), stream);
        edge_pass1_f<<<eb, 256, 0, stream>>>(src, dst, nf, S0, S1, n_edges);
        node1_f<<<NTOT / 256, 256, 0, stream>>>(nf, S0, S1, ws1, wn1, b1, ws2, wn2, S3);
        edge_pass2_f<<<eb, 256, 0, stream>>>(src, dst, S3, S2, n_edges);
        node2_f<<<NTOT / 256, 256, 0, stream>>>(S0, S2, S1, b2, b3, out1, S3, out2);
        gemm_f<<<dim3(GK / 256, KCHUNKS), 256, 0, stream>>>(S3, w3, out2);
    }
}

// Round 10
// 226.363 us; speedup vs baseline: 1.2804x; 1.0147x over previous
//
#include <hip/hip_runtime.h>

// GraphPolicyNetwork: 2-layer GraphSAGE (rank-1 weights -> scalar edge passes)
// + dense head [64x4096]@[4096x4096]. All tensors fp32 (proven round 4).
//
// R20: R19 (229.7us) exposed agn1_x = 48.7us @ VALU 39% / Occ 34% / HBM 3%:
// latency-bound, 1 block/CU (grid pinned at 256 buckets), all 16 waves stall
// together at the histogram->NHID barrier. Fixes:
// (1) NBINS 256->1024, BSZ 1024->256, agn blocks 256 thr -> 4 INDEPENDENT
//     blocks/CU (same 16 waves/CU): one block's gather phase overlaps the
//     others' NHID math. Scatter LDS-atomic contention also drops 4x.
//     CAP=2432 (mean 2048 + 8.5 sigma, guarded).
// (2) fast_tanh: IEEE div -> (1-t)*rcpf(1+t) (-8 VALU ops of ~20/eval x
//     33.5M evals). Error <= 1ulp, invisible at absmax 2e-3.
// gemm_x stays R11-exact (proven 50-52us; every rework attempt regressed).
// Fast path needs 20 MB d_ws; falls back to proven R4 pipeline if smaller.

#define NTOT (64 * 4096)      // 262144 total nodes = 2^18
#define NHID 128
#define GK   4096             // GEMM K == N_NODES
#define KCH  256              // K per chunk
#define KCHUNKS 16
#define NBINS 1024            // dst-range buckets
#define BSZ   256             // nodes per bucket (2^8)
#define BSH   8               // log2(BSZ)
#define CAP   2432            // bucket capacity (mean 2048 + ~8.5 sigma)
#define SCB   256             // scatter blocks

typedef unsigned int u32;

__device__ __forceinline__ float fast_tanh(float x) {
    float ax = fabsf(x);
    float t  = __expf(-2.0f * ax);
    float r  = (1.0f - t) * __builtin_amdgcn_rcpf(1.0f + t);
    return copysignf(r, x);
}

// ======================= FAST PATH (ws >= 20 MB) ==========================

// ---- scatter: two-phase per-block reservation into bucket segments ----
// Each thread owns <=8 edges, cached in registers across all 3 phases.
__global__ void __launch_bounds__(1024) scatter_x(const int* __restrict__ src,
                                                  const int* __restrict__ dst,
                                                  int n_edges,
                                                  int* __restrict__ edge_cnt,
                                                  u32* __restrict__ packed) {
    __shared__ int lc[NBINS];
    __shared__ int lbase[NBINS];
    int t = threadIdx.x;
    lc[t] = 0;                 // NBINS == 1024 == blockDim.x
    __syncthreads();
    int per = (n_edges + gridDim.x - 1) / gridDim.x;   // <= 8192
    int e0 = blockIdx.x * per;
    int e1 = min(e0 + per, n_edges);

    int dreg[8], sreg[8];
#pragma unroll
    for (int i = 0; i < 8; ++i) {
        int e = e0 + t + i * 1024;
        bool ok = e < e1;
        int d = ok ? dst[e] : -1;
        dreg[i] = d;
        sreg[i] = ok ? src[e] : 0;
        if (ok) atomicAdd(&lc[d >> BSH], 1);
    }
    __syncthreads();
    lbase[t] = atomicAdd(&edge_cnt[t], lc[t]);
    lc[t] = 0;
    __syncthreads();
#pragma unroll
    for (int i = 0; i < 8; ++i) {
        int d = dreg[i];
        if (d >= 0) {
            int b = d >> BSH;
            int pos = lbase[b] + atomicAdd(&lc[b], 1);
            if (pos < CAP)                    // p(overflow) ~ 0, fixed graph
                packed[(size_t)b * CAP + pos] =
                    ((u32)(d & (BSZ - 1)) << 18) | (u32)sreg[i];
        }
    }
}

// ---- fused agg1+node1: LDS histogram + per-node layer-1/2 math ----
// One 256-thr block per bucket; thread t = node t. 4 independent blocks/CU.
__global__ void __launch_bounds__(256) agn1_x(const u32* __restrict__ packed,
                                              const int* __restrict__ edge_cnt,
                                              const float* __restrict__ nf,
                                              const float* __restrict__ w_s1,
                                              const float* __restrict__ w_n1,
                                              const float* __restrict__ bb1,
                                              const float* __restrict__ w_s2,
                                              const float* __restrict__ w_n2,
                                              float* __restrict__ degf,
                                              float* __restrict__ selfp,
                                              float* __restrict__ sp) {
    __shared__ float lsum[BSZ];
    __shared__ float lcnt[BSZ];
    __shared__ float lws1[NHID], lwn1[NHID], lb1[NHID], lws2[NHID], lwn2[NHID];
    int t = threadIdx.x;
    int b = blockIdx.x;
    lsum[t] = 0.0f;
    lcnt[t] = 0.0f;
    if (t < NHID) {
        lws1[t] = w_s1[t];
        lwn1[t] = w_n1[t];
        lb1[t]  = bb1[t];
        lws2[t] = w_s2[t];
        lwn2[t] = w_n2[t];
    }
    __syncthreads();
    int en = min(edge_cnt[b], CAP);
    const u32* pk = packed + (size_t)b * CAP;
    for (int e = t; e < en; e += 256) {
        u32 p = pk[e];
        int local = (int)(p >> 18);
        atomicAdd(&lsum[local], nf[p & 0x3FFFFu]);
        atomicAdd(&lcnt[local], 1.0f);
    }
    __syncthreads();
    int v = b * BSZ + t;
    float cf = lcnt[t];
    float hn = lsum[t] / fmaxf(cf, 1.0f);
    float f  = nf[v];
    float a = 0.0f, s2 = 0.0f;
#pragma unroll 8
    for (int j = 0; j < NHID; ++j) {
        float th = fast_tanh(fmaf(f, lws1[j], fmaf(hn, lwn1[j], lb1[j])));
        a  = fmaf(th, lws2[j], a);
        s2 = fmaf(th, lwn2[j], s2);
    }
    degf[v]  = cf;
    selfp[v] = a;
    sp[v]    = s2;
}

// ---- fused agg2+node2: LDS histogram + out1 / h2t epilogue ----
__global__ void __launch_bounds__(256) agn2_x(const u32* __restrict__ packed,
                                              const int* __restrict__ edge_cnt,
                                              const float* __restrict__ spv,
                                              const float* __restrict__ selfp,
                                              const float* __restrict__ degf,
                                              const float* __restrict__ b2p,
                                              float* __restrict__ out1,
                                              float* __restrict__ h2t) {
    __shared__ float lsum[BSZ];
    int t = threadIdx.x;
    int b = blockIdx.x;
    lsum[t] = 0.0f;
    __syncthreads();
    int en = min(edge_cnt[b], CAP);
    const u32* pk = packed + (size_t)b * CAP;
    for (int e = t; e < en; e += 256) {
        u32 p = pk[e];
        atomicAdd(&lsum[p >> 18], spv[p & 0x3FFFFu]);
    }
    __syncthreads();
    int v = b * BSZ + t;
    float o = selfp[v] + lsum[t] / fmaxf(degf[v], 1.0f) + b2p[0];
    out1[v] = o;
    int r = v >> 12;     // graph (row) index 0..63
    int k = v & 4095;    // node-in-graph (K) index
    h2t[k * 64 + r] = fast_tanh(o);
}

// ---- GEMM (R11 exact, proven 49-52us): 64x64 tile, 8 waves x 8 rows ----
__global__ void __launch_bounds__(512, 4) gemm_x(const float* __restrict__ h2t,
                                                 const float* __restrict__ w3,
                                                 float* __restrict__ Cpart) {
    int lane = threadIdx.x & 63;
    int wv   = threadIdx.x >> 6;          // 0..7
    int col  = blockIdx.x * 64 + lane;
    int k0   = blockIdx.y * KCH;
    int row0 = __builtin_amdgcn_readfirstlane(wv * 8);

    const float* Ap = h2t + (size_t)k0 * 64 + row0;
    const float* wp = w3 + (size_t)k0 * GK + col;

    float acc[8];
#pragma unroll
    for (int r = 0; r < 8; ++r) acc[r] = 0.0f;

    float bvA[8], bvB[8];
    float avA[8], avB[8];

#pragma unroll
    for (int j = 0; j < 8; ++j) bvA[j] = wp[(size_t)j * GK];
#pragma unroll
    for (int r = 0; r < 8; ++r) avA[r] = Ap[r];

    for (int kk = 0; kk < KCH; kk += 16) {
#pragma unroll
        for (int j = 0; j < 8; ++j) bvB[j] = wp[(size_t)(kk + 8 + j) * GK];
#pragma unroll
        for (int j = 0; j < 8; ++j) {
            const float* An = Ap + (size_t)(kk + j + 1) * 64;
            if ((j & 1) == 0) {
#pragma unroll
                for (int r = 0; r < 8; ++r) avB[r] = An[r];
                float b = bvA[j];
#pragma unroll
                for (int r = 0; r < 8; ++r) acc[r] = fmaf(avA[r], b, acc[r]);
            } else {
#pragma unroll
                for (int r = 0; r < 8; ++r) avA[r] = An[r];
                float b = bvA[j];
#pragma unroll
                for (int r = 0; r < 8; ++r) acc[r] = fmaf(avB[r], b, acc[r]);
            }
        }
        if (kk + 16 < KCH) {
#pragma unroll
            for (int j = 0; j < 8; ++j) bvA[j] = wp[(size_t)(kk + 16 + j) * GK];
        }
#pragma unroll
        for (int j = 0; j < 8; ++j) {
            int kn = kk + 8 + j + 1;
            if (kn > KCH - 1) kn = KCH - 1;
            const float* An = Ap + (size_t)kn * 64;
            if ((j & 1) == 0) {
#pragma unroll
                for (int r = 0; r < 8; ++r) avB[r] = An[r];
                float b = bvB[j];
#pragma unroll
                for (int r = 0; r < 8; ++r) acc[r] = fmaf(avA[r], b, acc[r]);
            } else {
#pragma unroll
                for (int r = 0; r < 8; ++r) avA[r] = An[r];
                float b = bvB[j];
#pragma unroll
                for (int r = 0; r < 8; ++r) acc[r] = fmaf(avB[r], b, acc[r]);
            }
        }
    }

    float* Cp = Cpart + (size_t)blockIdx.y * NTOT + (size_t)row0 * GK + col;
#pragma unroll
    for (int r = 0; r < 8; ++r) Cp[(size_t)r * GK] = acc[r];
}

// ---- reduce K-chunk partials + b3 -> out2 (float4) ----
__global__ void reduce_x(const float4* __restrict__ Cpart, const float4* __restrict__ b3v,
                         float4* __restrict__ out2) {
    int v = blockIdx.x * blockDim.x + threadIdx.x;   // float4 index, NTOT/4
    float4 s = b3v[v & 1023];
#pragma unroll
    for (int kc = 0; kc < KCHUNKS; ++kc) {
        float4 c = Cpart[(size_t)kc * (NTOT / 4) + v];
        s.x += c.x; s.y += c.y; s.z += c.z; s.w += c.w;
    }
    out2[v] = s;
}

// ================== FALLBACK PATH (proven R4 pipeline) ====================

__global__ void edge_pass1_f(const int* __restrict__ src, const int* __restrict__ dst,
                             const float* __restrict__ nf, float* __restrict__ agg,
                             float* __restrict__ deg, int n_edges) {
    int e = blockIdx.x * blockDim.x + threadIdx.x;
    if (e >= n_edges) return;
    int s = src[e], d = dst[e];
    atomicAdd(&agg[d], nf[s]);
    atomicAdd(&deg[d], 1.0f);
}

__global__ void node1_f(const float* __restrict__ nf, float* s0,
                        const float* __restrict__ deg,
                        const float* __restrict__ w_s1, const float* __restrict__ w_n1,
                        const float* __restrict__ bb1,
                        const float* __restrict__ w_s2, const float* __restrict__ w_n2,
                        float* __restrict__ sp) {
    __shared__ float lws1[NHID], lwn1[NHID], lb1[NHID], lws2[NHID], lwn2[NHID];
    int tid = threadIdx.x;
    if (tid < NHID) {
        lws1[tid] = w_s1[tid];
        lwn1[tid] = w_n1[tid];
        lb1[tid]  = bb1[tid];
        lws2[tid] = w_s2[tid];
        lwn2[tid] = w_n2[tid];
    }
    __syncthreads();
    int v = blockIdx.x * blockDim.x + tid;
    float f  = nf[v];
    float hn = s0[v] / fmaxf(deg[v], 1.0f);
    float a = 0.0f, s = 0.0f;
#pragma unroll 8
    for (int j = 0; j < NHID; ++j) {
        float t = fast_tanh(fmaf(f, lws1[j], fmaf(hn, lwn1[j], lb1[j])));
        a = fmaf(t, lws2[j], a);
        s = fmaf(t, lwn2[j], s);
    }
    s0[v] = a;
    sp[v] = s;
}

__global__ void edge_pass2_f(const int* __restrict__ src, const int* __restrict__ dst,
                             const float* __restrict__ sp, float* __restrict__ agg2,
                             int n_edges) {
    int e = blockIdx.x * blockDim.x + threadIdx.x;
    if (e >= n_edges) return;
    atomicAdd(&agg2[dst[e]], sp[src[e]]);
}

__global__ void node2_f(const float* __restrict__ s0, const float* __restrict__ agg2,
                        const float* __restrict__ deg, const float* __restrict__ b2p,
                        const float* __restrict__ b3p,
                        float* __restrict__ out1, float* __restrict__ h2t,
                        float* __restrict__ out2) {
    int v = blockIdx.x * blockDim.x + threadIdx.x;
    float o = s0[v] + agg2[v] / fmaxf(deg[v], 1.0f) + b2p[0];
    out1[v] = o;
    int r = v >> 12;
    int k = v & 4095;
    h2t[k * 64 + r] = fast_tanh(o);
    out2[v] = b3p[v & 4095];
}

__global__ void __launch_bounds__(256) gemm_f(const float* __restrict__ h2t,
                                              const float* __restrict__ w3,
                                              float* __restrict__ out2) {
    int n  = blockIdx.x * 256 + threadIdx.x;
    int k0 = blockIdx.y * KCH;
    float acc[64];
#pragma unroll
    for (int r = 0; r < 64; ++r) acc[r] = 0.0f;
    for (int k = k0; k < k0 + KCH; ++k) {
        float bv = w3[(size_t)k * GK + n];
        const float* Ak = h2t + k * 64;
#pragma unroll
        for (int r = 0; r < 64; ++r) acc[r] = fmaf(Ak[r], bv, acc[r]);
    }
#pragma unroll
    for (int r = 0; r < 64; ++r) atomicAdd(&out2[r * GK + n], acc[r]);
}

// ==========================================================================

extern "C" void kernel_launch(void* const* d_in, const int* in_sizes, int n_in,
                              void* d_out, int out_size, void* d_ws, size_t ws_size,
                              hipStream_t stream) {
    const float* nf  = (const float*)d_in[0];
    const int*   src = (const int*)d_in[1];
    const int*   dst = (const int*)d_in[2];
    const float* ws1 = (const float*)d_in[3];
    const float* wn1 = (const float*)d_in[4];
    const float* b1  = (const float*)d_in[5];
    const float* ws2 = (const float*)d_in[6];
    const float* wn2 = (const float*)d_in[7];
    const float* b2  = (const float*)d_in[8];
    const float* w3  = (const float*)d_in[9];
    const float* b3  = (const float*)d_in[10];
    float* out1 = (float*)d_out;
    float* out2 = (float*)d_out + NTOT;

    int n_edges = in_sizes[1];
    int eb = (n_edges + 255) / 256;

    if (ws_size >= (size_t)20 * 1024 * 1024 && n_edges <= (1 << 21)) {
        // -------- fast path: 20 MB layout --------
        // packed  [0, 9.97M)  (NBINS*CAP u32 = 9961472 B)
        // degf    [10M, 11M)  selfp [11M, 12M)  sp [12M, 13M)
        // h2t     [16M, 17M)
        // edge_cnt @ 17M      (NBINS ints = 4 KB)
        // Cpart overlays [0, 16M): packed/degf/selfp/sp dead when gemm runs;
        // h2t at 16M is outside Cpart (ends exactly at 16777216).
        char*  base     = (char*)d_ws;
        u32*   packed   = (u32*)base;
        float* degf     = (float*)(base + 10485760);
        float* selfp    = (float*)(base + 11534336);
        float* spbuf    = (float*)(base + 12582912);
        float* h2t      = (float*)(base + 16777216);
        int*   edge_cnt = (int*)(base + 17825792);
        float* Cpart    = (float*)base;

        (void)hipMemsetAsync(edge_cnt, 0, NBINS * sizeof(int), stream);
        scatter_x<<<SCB, 1024, 0, stream>>>(src, dst, n_edges, edge_cnt, packed);
        agn1_x<<<NBINS, BSZ, 0, stream>>>(packed, edge_cnt, nf, ws1, wn1, b1,
                                          ws2, wn2, degf, selfp, spbuf);
        agn2_x<<<NBINS, BSZ, 0, stream>>>(packed, edge_cnt, spbuf, selfp, degf,
                                          b2, out1, h2t);
        gemm_x<<<dim3(GK / 64, KCHUNKS), 512, 0, stream>>>(h2t, w3, Cpart);
        reduce_x<<<NTOT / 4 / 256, 256, 0, stream>>>((const float4*)Cpart,
                                                     (const float4*)b3, (float4*)out2);
    } else {
        // -------- fallback: proven R4 pipeline (4.19 MB) --------
        float* ws = (float*)d_ws;
        float* S0 = ws;            // agg -> selfpart
        float* S1 = ws + 1 * NTOT; // deg
        float* S2 = ws + 2 * NTOT; // agg2
        float* S3 = ws + 3 * NTOT; // sp -> h2t

        (void)hipMemsetAsync(S0, 0, (size_t)3 * NTOT * sizeof(float), stream);
        edge_pass1_f<<<eb, 256, 0, stream>>>(src, dst, nf, S0, S1, n_edges);
        node1_f<<<NTOT / 256, 256, 0, stream>>>(nf, S0, S1, ws1, wn1, b1, ws2, wn2, S3);
        edge_pass2_f<<<eb, 256, 0, stream>>>(src, dst, S3, S2, n_edges);
        node2_f<<<NTOT / 256, 256, 0, stream>>>(S0, S2, S1, b2, b3, out1, S3, out2);
        gemm_f<<<dim3(GK / 256, KCHUNKS), 256, 0, stream>>>(S3, w3, out2);
    }
}